// Round 10
// baseline (37.066 us; speedup 1.0000x reference)
//
#include <hip/hip_runtime.h>
#include <hip/hip_bf16.h>

// N=8192, D=128. loss = mean(-log(exp(sims_ii)) + 0.5*(log(den_i)+log(den_j)))
// sims = (A @ T^T) * exp(temp); den = row/col sums of exp(sims), diag zeroed.
//
// R9: 8 phases x 1 tile (16 cols), triple-buffered B, prefetch distance 3.
// Buffer-reuse WAR deps pin the software pipeline (no hoisting). ~110 live
// regs -> target 4 waves/SIMD. MX-fp8 K=128 mfma (R8-verified, absmax 0.0).
// Rules carried: independent wave-tiles, zero LDS, zero barriers, NO
// launch_bounds min-waves cap (R3/R6 spills), diag fp32-exact in finalize.
//
// ws layout (bytes):
//   [0,      1 MiB)  A fp8 e4m3 * exp(temp)*log2e, [r16 0..511][lane 0..63][32B]
//   [1 MiB,  2 MiB)  T fp8 e4m3, same layout, unscaled
//   [2 MiB,  4 MiB)  den_i partials float[8192][64]   (slot = col-strip j)
//   [4 MiB,  8 MiB)  den_j partials float[8192][128]  (slot = row-strip rs)
//   [8 MiB, +32 KiB) per-row loss float[8192]

typedef __attribute__((ext_vector_type(8))) int   v8i;
typedef __attribute__((ext_vector_type(4))) float f32x4;

#define SCALE_ONE 0x7F7F7F7F   // e8m0 1.0 in every byte (opsel-proof)

__device__ __forceinline__ float fast_exp2(float x) {
#if __has_builtin(__builtin_amdgcn_exp2f)
    return __builtin_amdgcn_exp2f(x);      // bare v_exp_f32
#else
    return __expf(x * 0.69314718056f);
#endif
}

// VALU-pipe partial-sum step: v += lane(l-n) within each 16-lane DPP row,
// 0-filled at the edge. After 1,2,4,8 lane 15 holds the 16-lane sum.
// (HW-verified R4-R9.)
template <int CTRL>
__device__ __forceinline__ float dpp_sr_add(float v) {
    int s = __builtin_amdgcn_update_dpp(0, __float_as_int(v), CTRL, 0xf, 0xf, true);
    return v + __int_as_float(s);
}
__device__ __forceinline__ float row16_sum(float v) {
    v = dpp_sr_add<0x111>(v);   // row_shr:1
    v = dpp_sr_add<0x112>(v);   // row_shr:2
    v = dpp_sr_add<0x114>(v);   // row_shr:4
    v = dpp_sr_add<0x118>(v);   // row_shr:8
    return v;                   // valid in lane 15 of each 16-lane row
}

// ---------------------------------------------------------------- kernel 1
// fp8 fragment-major pack for mfma_scale 16x16x128 (R8/R9-verified):
//   lane l of tile r16 holds M[r16*16 + (l&15)][(l>>4)*32 .. +32]  (32 B).
// A pre-scaled by exp(temp)*log2(e); T unscaled.
__global__ void convert_pack(const float* __restrict__ a,
                             const float* __restrict__ t,
                             const float* __restrict__ temps,
                             unsigned char* __restrict__ oa,
                             unsigned char* __restrict__ ot) {
    int idx = blockIdx.x * 256 + threadIdx.x;          // 0 .. 131071
    const bool isT = (idx >> 16) != 0;
    const float* src = isT ? t : a;
    unsigned char* dst = isT ? ot : oa;
    const float s = isT ? 1.0f : (__expf(temps[0]) * 1.44269504f);
    int loc = idx & 65535;
    int tile = loc >> 7, sub = loc & 127;
    int lane = sub >> 1, h = sub & 1;
    int row = tile * 16 + (lane & 15);
    int k0  = (lane >> 4) * 32 + h * 16;
    const float4* s4 = reinterpret_cast<const float4*>(src + row * 128 + k0);
    unsigned w[4];
#pragma unroll
    for (int q = 0; q < 4; ++q) {
        float4 f = s4[q];
        int v = __builtin_amdgcn_cvt_pk_fp8_f32(f.x * s, f.y * s, 0, false);
        v = __builtin_amdgcn_cvt_pk_fp8_f32(f.z * s, f.w * s, v, true);
        w[q] = (unsigned)v;
    }
    *reinterpret_cast<uint4*>(dst + tile * 2048 + lane * 32 + h * 16) =
        make_uint4(w[0], w[1], w[2], w[3]);
}

// ---------------------------------------------------------------- kernel 2
// Independent 64x128 wave-tiles, zero LDS, zero barriers. af[4] pinned
// (32 VGPR). B strip = 8 tiles of 16 cols; 8 phases, triple-buffered
// (b0/b1/b2, 8 VGPR each), prefetch distance 3: load(p+3) issued right
// after compute(p) frees its buffer (WAR pins schedule). acc 16 regs
// reused per phase. ~110 live -> 4 waves/SIMD expected.
#define LDB(BUF, P)  BUF = *reinterpret_cast<const v8i*>(tb + (P) * 2048);

#define PH(BUF, P)                                                      \
  {                                                                     \
    f32x4 acc[4];                                                       \
    _Pragma("unroll") for (int m = 0; m < 4; ++m)                       \
        acc[m] = (f32x4){0.f, 0.f, 0.f, 0.f};                           \
    _Pragma("unroll") for (int m = 0; m < 4; ++m)                       \
        acc[m] = __builtin_amdgcn_mfma_scale_f32_16x16x128_f8f6f4(      \
            af[m], BUF, acc[m], 0, 0, 0, SCALE_ONE, 0, SCALE_ONE);      \
    float csum = 0.f;                                                   \
    _Pragma("unroll") for (int m = 0; m < 4; ++m)                       \
      _Pragma("unroll") for (int jj = 0; jj < 4; ++jj) {                \
        float v = fast_exp2(acc[m][jj]);                                \
        rsum[m][jj] += v;                                               \
        csum += v;                                                      \
      }                                                                 \
    csum += __shfl_xor(csum, 16); csum += __shfl_xor(csum, 32);         \
    if (lane < 16) {                                                    \
      int col = (j * 8 + (P)) * 16 + lcol;                              \
      Pj[col * 128 + rs] = csum;                                        \
    }                                                                   \
  }

__global__ void __launch_bounds__(256)
gemm_exp(const unsigned char* __restrict__ Ap, const unsigned char* __restrict__ Tp,
         float* __restrict__ Pi, float* __restrict__ Pj) {
    const int tid = threadIdx.x;
    const int wave = tid >> 6, lane = tid & 63;
    const int krow = lane >> 4, lcol = lane & 15;
    const int fid = blockIdx.x;                        // 0..2047
    const int vid = (fid & 7) * 256 + (fid >> 3);      // bijective (2048%8==0)
    const int j  = vid >> 5;                           // col-strip (128 cols) 0..63
    const int rg = vid & 31;                           // row-group (256 rows) 0..31
    const int rs = rg * 4 + wave;                      // row-strip (64 rows) 0..127

    // A fragments: 4 x 32B/lane coalesced loads, held for all phases
    v8i af[4];
#pragma unroll
    for (int m = 0; m < 4; ++m)
        af[m] = *reinterpret_cast<const v8i*>(Ap + (rs * 4 + m) * 2048 + lane * 32);

    const unsigned char* tb = Tp + j * 8 * 2048 + lane * 32;

    float rsum[4][4] = {};
    v8i b0, b1, b2;

    // prologue: phases 0..2 in flight
    LDB(b0, 0); LDB(b1, 1); LDB(b2, 2);

    PH(b0, 0); LDB(b0, 3);
    PH(b1, 1); LDB(b1, 4);
    PH(b2, 2); LDB(b2, 5);
    PH(b0, 3); LDB(b0, 6);
    PH(b1, 4); LDB(b1, 7);
    PH(b2, 5);
    PH(b0, 6);
    PH(b1, 7);

    // row sums over this wave's 128 cols: DPP reduce, lane 15 of each krow row
#pragma unroll
    for (int m = 0; m < 4; ++m)
#pragma unroll
        for (int jj = 0; jj < 4; ++jj) {
            float v = row16_sum(rsum[m][jj]);
            if (lcol == 15) {
                int row = rs * 64 + m * 16 + krow * 4 + jj;
                Pi[row * 64 + j] = v;
            }
        }
}

// ---------------------------------------------------------------- kernel 3
// One wave per row, 4 rows/block; diag dot recomputed in fp32 (exact
// numerator), subtracted from both fp8-derived denominators.
__global__ void finalize_rows(const float* __restrict__ a, const float* __restrict__ t,
                              const float* __restrict__ temps,
                              const float* __restrict__ Pi, const float* __restrict__ Pj,
                              float* __restrict__ loss) {
    const int r = blockIdx.x * 4 + (threadIdx.x >> 6);
    const int l = threadIdx.x & 63;
    const float sc = __expf(temps[0]);
    float deni = Pi[r * 64 + l];
    float denj = Pj[r * 128 + l] + Pj[r * 128 + 64 + l];
    float dotp = a[r * 128 + l] * t[r * 128 + l]
               + a[r * 128 + 64 + l] * t[r * 128 + 64 + l];
#pragma unroll
    for (int m = 1; m < 64; m <<= 1) {
        deni += __shfl_xor(deni, m);
        denj += __shfl_xor(denj, m);
        dotp += __shfl_xor(dotp, m);
    }
    if (l == 0) {
        float diag = __expf(sc * dotp);
        float di = fmaxf(deni - diag, 1e-20f);
        float dj = fmaxf(denj - diag, 1e-20f);
        loss[r] = -sc * dotp + 0.5f * (__logf(di) + __logf(dj));
    }
}

// ---------------------------------------------------------------- kernel 4
__global__ void reduce_loss(const float* __restrict__ loss, float* __restrict__ out) {
    __shared__ float wsum[16];
    const int tid = threadIdx.x;   // 1024
    float s = 0.f;
#pragma unroll
    for (int i = 0; i < 8; ++i) s += loss[tid + i * 1024];
#pragma unroll
    for (int m = 1; m < 64; m <<= 1) s += __shfl_xor(s, m);
    if ((tid & 63) == 0) wsum[tid >> 6] = s;
    __syncthreads();
    if (tid == 0) {
        float acc = 0.f;
#pragma unroll
        for (int w = 0; w < 16; ++w) acc += wsum[w];
        out[0] = acc * (1.0f / 8192.0f);
    }
}

extern "C" void kernel_launch(void* const* d_in, const int* in_sizes, int n_in,
                              void* d_out, int out_size, void* d_ws, size_t ws_size,
                              hipStream_t stream) {
    const float* a     = (const float*)d_in[0];
    const float* t     = (const float*)d_in[1];
    const float* temps = (const float*)d_in[2];
    float* out = (float*)d_out;

    char* ws = (char*)d_ws;
    unsigned char* Ap = (unsigned char*)(ws);
    unsigned char* Tp = (unsigned char*)(ws + (1u << 20));
    float* Pi  = (float*)(ws + (2u << 20));
    float* Pj  = (float*)(ws + (4u << 20));
    float* los = (float*)(ws + (8u << 20));

    convert_pack<<<512, 256, 0, stream>>>(a, t, temps, Ap, Tp);
    gemm_exp<<<2048, 256, 0, stream>>>(Ap, Tp, Pi, Pj);
    finalize_rows<<<2048, 256, 0, stream>>>(a, t, temps, Pi, Pj, los);
    reduce_loss<<<1, 1024, 0, stream>>>(los, out);
}

// Round 11
// 33.952 us; speedup vs baseline: 1.0917x; 1.0917x over previous
//
#include <hip/hip_runtime.h>
#include <hip/hip_bf16.h>

// N=8192, D=128. loss = mean(-log(exp(sims_ii)) + 0.5*(log(den_i)+log(den_j)))
// sims = (A @ T^T) * exp(temp); den = row/col sums of exp(sims), diag zeroed.
//
// R10 = R8's proven structure (34.4 us; R9's finer phases regressed) with
// 64x256 wave tiles: 8 dual-buffered 32-col phases per wave, halving wave
// count -> prologue/epilogue amortized 2x, A traffic halved.
// Rules carried: independent wave-tiles, zero LDS, zero barriers, NO
// launch_bounds min-waves cap (R3/R6 spills), diag fp32-exact in finalize.
//
// ws layout (bytes):
//   [0,      1 MiB)  A fp8 e4m3 * exp(temp)*log2e, [r16 0..511][lane 0..63][32B]
//   [1 MiB,  2 MiB)  T fp8 e4m3, same layout, unscaled
//   [2 MiB,  3 MiB)  den_i partials float[8192][32]   (slot = col-strip j)
//   [4 MiB,  8 MiB)  den_j partials float[8192][128]  (slot = row-strip rs)
//   [8 MiB, +32 KiB) per-row loss float[8192]

typedef __attribute__((ext_vector_type(8))) int   v8i;
typedef __attribute__((ext_vector_type(4))) float f32x4;

#define SCALE_ONE 0x7F7F7F7F   // e8m0 1.0 in every byte (opsel-proof)

__device__ __forceinline__ float fast_exp2(float x) {
#if __has_builtin(__builtin_amdgcn_exp2f)
    return __builtin_amdgcn_exp2f(x);      // bare v_exp_f32
#else
    return __expf(x * 0.69314718056f);
#endif
}

// VALU-pipe partial-sum step: v += lane(l-n) within each 16-lane DPP row,
// 0-filled at the edge. After 1,2,4,8 lane 15 holds the 16-lane sum.
// (HW-verified R4-R10.)
template <int CTRL>
__device__ __forceinline__ float dpp_sr_add(float v) {
    int s = __builtin_amdgcn_update_dpp(0, __float_as_int(v), CTRL, 0xf, 0xf, true);
    return v + __int_as_float(s);
}
__device__ __forceinline__ float row16_sum(float v) {
    v = dpp_sr_add<0x111>(v);   // row_shr:1
    v = dpp_sr_add<0x112>(v);   // row_shr:2
    v = dpp_sr_add<0x114>(v);   // row_shr:4
    v = dpp_sr_add<0x118>(v);   // row_shr:8
    return v;                   // valid in lane 15 of each 16-lane row
}

// ---------------------------------------------------------------- kernel 1
// fp8 fragment-major pack for mfma_scale 16x16x128 (R8/R9-verified):
//   lane l of tile r16 holds M[r16*16 + (l&15)][(l>>4)*32 .. +32]  (32 B).
// A pre-scaled by exp(temp)*log2(e); T unscaled.
__global__ void convert_pack(const float* __restrict__ a,
                             const float* __restrict__ t,
                             const float* __restrict__ temps,
                             unsigned char* __restrict__ oa,
                             unsigned char* __restrict__ ot) {
    int idx = blockIdx.x * 256 + threadIdx.x;          // 0 .. 131071
    const bool isT = (idx >> 16) != 0;
    const float* src = isT ? t : a;
    unsigned char* dst = isT ? ot : oa;
    const float s = isT ? 1.0f : (__expf(temps[0]) * 1.44269504f);
    int loc = idx & 65535;
    int tile = loc >> 7, sub = loc & 127;
    int lane = sub >> 1, h = sub & 1;
    int row = tile * 16 + (lane & 15);
    int k0  = (lane >> 4) * 32 + h * 16;
    const float4* s4 = reinterpret_cast<const float4*>(src + row * 128 + k0);
    unsigned w[4];
#pragma unroll
    for (int q = 0; q < 4; ++q) {
        float4 f = s4[q];
        int v = __builtin_amdgcn_cvt_pk_fp8_f32(f.x * s, f.y * s, 0, false);
        v = __builtin_amdgcn_cvt_pk_fp8_f32(f.z * s, f.w * s, v, true);
        w[q] = (unsigned)v;
    }
    *reinterpret_cast<uint4*>(dst + tile * 2048 + lane * 32 + h * 16) =
        make_uint4(w[0], w[1], w[2], w[3]);
}

// ---------------------------------------------------------------- kernel 2
// Independent 64x256 wave-tiles, zero LDS, zero barriers. af[4] pinned
// (32 VGPR); B dual-buffered (bfA/bfB, 16 VGPR each) one 32-col phase
// ahead (R8 pattern). 8 phases x (2 loads, 8 mfma K=128, 32 exp2, sums).
#define PHASE(BF, COLBASE)                                              \
  {                                                                     \
    f32x4 acc[4][2];                                                    \
    _Pragma("unroll") for (int m = 0; m < 4; ++m)                       \
      _Pragma("unroll") for (int n = 0; n < 2; ++n)                     \
        acc[m][n] = (f32x4){0.f, 0.f, 0.f, 0.f};                        \
    _Pragma("unroll") for (int m = 0; m < 4; ++m)                       \
      _Pragma("unroll") for (int n = 0; n < 2; ++n)                     \
        acc[m][n] = __builtin_amdgcn_mfma_scale_f32_16x16x128_f8f6f4(   \
            af[m], BF[n], acc[m][n], 0, 0, 0, SCALE_ONE, 0, SCALE_ONE); \
    float csum[2] = {0.f, 0.f};                                         \
    _Pragma("unroll") for (int m = 0; m < 4; ++m)                       \
      _Pragma("unroll") for (int n = 0; n < 2; ++n)                     \
        _Pragma("unroll") for (int jj = 0; jj < 4; ++jj) {              \
          float v = fast_exp2(acc[m][n][jj]);                           \
          rsum[m][jj] += v;                                             \
          csum[n] += v;                                                 \
        }                                                               \
    _Pragma("unroll") for (int n = 0; n < 2; ++n) {                     \
      float v = csum[n];                                                \
      v += __shfl_xor(v, 16); v += __shfl_xor(v, 32);                   \
      if (lane < 16) {                                                  \
        int col = (COLBASE + n) * 16 + lcol;                            \
        Pj[col * 128 + rs] = v;                                         \
      }                                                                 \
    }                                                                   \
  }

__global__ void __launch_bounds__(256)
gemm_exp(const unsigned char* __restrict__ Ap, const unsigned char* __restrict__ Tp,
         float* __restrict__ Pi, float* __restrict__ Pj) {
    const int tid = threadIdx.x;
    const int wave = tid >> 6, lane = tid & 63;
    const int krow = lane >> 4, lcol = lane & 15;
    const int fid = blockIdx.x;                        // 0..1023
    const int vid = (fid & 7) * 128 + (fid >> 3);      // bijective (1024%8==0)
    const int j  = vid >> 5;                           // col-strip (256 cols) 0..31
    const int rg = vid & 31;                           // row-group (256 rows) 0..31
    const int rs = rg * 4 + wave;                      // row-strip (64 rows) 0..127

    // A fragments: 4 x 32B/lane coalesced loads, held for all 8 phases
    v8i af[4];
#pragma unroll
    for (int m = 0; m < 4; ++m)
        af[m] = *reinterpret_cast<const v8i*>(Ap + (rs * 4 + m) * 2048 + lane * 32);

    const unsigned char* tb = Tp + j * 16 * 2048 + lane * 32;  // 16 tiles/strip

    float rsum[4][4] = {};
    v8i bfA[2], bfB[2];

    // prologue: phase-0 B (16-col tiles 0,1)
    bfA[0] = *reinterpret_cast<const v8i*>(tb);
    bfA[1] = *reinterpret_cast<const v8i*>(tb + 2048);

#pragma unroll 1
    for (int ph2 = 0; ph2 < 4; ++ph2) {
        const unsigned char* base = tb + ph2 * 8192;   // 4 tiles per iteration

        // prefetch odd phase (tiles +2,+3) — covered by PHASE(bfA)
        bfB[0] = *reinterpret_cast<const v8i*>(base + 2 * 2048);
        bfB[1] = *reinterpret_cast<const v8i*>(base + 3 * 2048);

        PHASE(bfA, j * 16 + ph2 * 4);

        // prefetch next even phase — covered by PHASE(bfB)
        if (ph2 < 3) {
            bfA[0] = *reinterpret_cast<const v8i*>(base + 8192);
            bfA[1] = *reinterpret_cast<const v8i*>(base + 8192 + 2048);
        }

        PHASE(bfB, j * 16 + ph2 * 4 + 2);
    }

    // row sums over this wave's 256 cols: DPP reduce, lane 15 of each krow row
#pragma unroll
    for (int m = 0; m < 4; ++m)
#pragma unroll
        for (int jj = 0; jj < 4; ++jj) {
            float v = row16_sum(rsum[m][jj]);
            if (lcol == 15) {
                int row = rs * 64 + m * 16 + krow * 4 + jj;
                Pi[row * 32 + j] = v;
            }
        }
}

// ---------------------------------------------------------------- kernel 3
// One wave per row, 4 rows/block; diag dot recomputed in fp32 (exact
// numerator), subtracted from both fp8-derived denominators.
__global__ void finalize_rows(const float* __restrict__ a, const float* __restrict__ t,
                              const float* __restrict__ temps,
                              const float* __restrict__ Pi, const float* __restrict__ Pj,
                              float* __restrict__ loss) {
    const int r = blockIdx.x * 4 + (threadIdx.x >> 6);
    const int l = threadIdx.x & 63;
    const float sc = __expf(temps[0]);
    float deni = (l < 32) ? Pi[r * 32 + l] : 0.f;
    float denj = Pj[r * 128 + l] + Pj[r * 128 + 64 + l];
    float dotp = a[r * 128 + l] * t[r * 128 + l]
               + a[r * 128 + 64 + l] * t[r * 128 + 64 + l];
#pragma unroll
    for (int m = 1; m < 64; m <<= 1) {
        deni += __shfl_xor(deni, m);
        denj += __shfl_xor(denj, m);
        dotp += __shfl_xor(dotp, m);
    }
    if (l == 0) {
        float diag = __expf(sc * dotp);
        float di = fmaxf(deni - diag, 1e-20f);
        float dj = fmaxf(denj - diag, 1e-20f);
        loss[r] = -sc * dotp + 0.5f * (__logf(di) + __logf(dj));
    }
}

// ---------------------------------------------------------------- kernel 4
__global__ void reduce_loss(const float* __restrict__ loss, float* __restrict__ out) {
    __shared__ float wsum[16];
    const int tid = threadIdx.x;   // 1024
    float s = 0.f;
#pragma unroll
    for (int i = 0; i < 8; ++i) s += loss[tid + i * 1024];
#pragma unroll
    for (int m = 1; m < 64; m <<= 1) s += __shfl_xor(s, m);
    if ((tid & 63) == 0) wsum[tid >> 6] = s;
    __syncthreads();
    if (tid == 0) {
        float acc = 0.f;
#pragma unroll
        for (int w = 0; w < 16; ++w) acc += wsum[w];
        out[0] = acc * (1.0f / 8192.0f);
    }
}

extern "C" void kernel_launch(void* const* d_in, const int* in_sizes, int n_in,
                              void* d_out, int out_size, void* d_ws, size_t ws_size,
                              hipStream_t stream) {
    const float* a     = (const float*)d_in[0];
    const float* t     = (const float*)d_in[1];
    const float* temps = (const float*)d_in[2];
    float* out = (float*)d_out;

    char* ws = (char*)d_ws;
    unsigned char* Ap = (unsigned char*)(ws);
    unsigned char* Tp = (unsigned char*)(ws + (1u << 20));
    float* Pi  = (float*)(ws + (2u << 20));
    float* Pj  = (float*)(ws + (4u << 20));
    float* los = (float*)(ws + (8u << 20));

    convert_pack<<<512, 256, 0, stream>>>(a, t, temps, Ap, Tp);
    gemm_exp<<<1024, 256, 0, stream>>>(Ap, Tp, Pi, Pj);
    finalize_rows<<<2048, 256, 0, stream>>>(a, t, temps, Pi, Pj, los);
    reduce_loss<<<1, 1024, 0, stream>>>(los, out);
}